// Round 1
// baseline (824.751 us; speedup 1.0000x reference)
//
#include <hip/hip_runtime.h>

#define NBLK 8
#define BSZ 128
#define HDIM 1024
#define MROWS 32768          // B*S = 8*4096
#define WGS_PER_BLK 64
#define TILES_PER_BLK 256    // MROWS / 128 rows-per-tile

typedef float f32x4 __attribute__((ext_vector_type(4)));
typedef short s16x8 __attribute__((ext_vector_type(8)));
typedef __bf16 bf16x8 __attribute__((ext_vector_type(8)));

__device__ __forceinline__ unsigned short f2bf(float f) {
    // round-to-nearest-even fp32 -> bf16 (bit pattern)
    union { float f; unsigned u; } v; v.f = f;
    return (unsigned short)((v.u + 0x7FFFu + ((v.u >> 16) & 1u)) >> 16);
}

__global__ __launch_bounds__(512, 4) void cbl_main(
    const float* __restrict__ xre, const float* __restrict__ xim,
    const float* __restrict__ wgt, float* __restrict__ out)
{
    // W for this block, bf16, stored as 64 pre-formed B-fragments:
    // frag id fid = (cg*4 + ks)*2 + comp ; lane slot = lane*16B
    // lane l of frag holds W[k = ks*32 + (l>>4)*8 + j][o = cg*16 + (l&15)], j=0..7
    __shared__ short wlds[32768];   // 64 KB

    const int tid  = threadIdx.x;
    const int lane = tid & 63;
    const int wv   = tid >> 6;      // wave 0..7
    const int lq   = lane >> 4;     // quarter 0..3
    const int ll   = lane & 15;

    const int n   = blockIdx.x / WGS_PER_BLK;   // weight block
    const int wgr = blockIdx.x % WGS_PER_BLK;

    // ---- stage W (block n) into LDS as bf16 B-fragments (once per WG) ----
    #pragma unroll
    for (int ff = 0; ff < 8; ++ff) {
        const int fid  = wv * 8 + ff;
        const int comp = fid & 1;          // 0 = wr, 1 = wi
        const int ks   = (fid >> 1) & 3;   // k-step (32 k each)
        const int cg   = fid >> 3;         // col group (16 cols)
        const int k0   = ks * 32 + lq * 8;
        const int o    = cg * 16 + ll;
        const float* src = wgt + (size_t)((n * BSZ + k0) * BSZ + o) * 2 + comp;
        s16x8 bits;
        #pragma unroll
        for (int j = 0; j < 8; ++j)
            bits[j] = (short)f2bf(src[(size_t)j * (BSZ * 2)]);
        *(s16x8*)&wlds[fid * 512 + lane * 8] = bits;
    }
    __syncthreads();

    for (int tt = wgr; tt < TILES_PER_BLK; tt += WGS_PER_BLK) {
        const int r0 = tt * 128 + wv * 16;   // this wave's 16 rows

        f32x4 accre[8], accim[8];
        #pragma unroll
        for (int cg = 0; cg < 8; ++cg) {
            accre[cg] = (f32x4){0.f, 0.f, 0.f, 0.f};
            accim[cg] = (f32x4){0.f, 0.f, 0.f, 0.f};
        }

        // A-fragment: lane holds row (r0 + ll), k-octet lq  (8 consecutive k)
        const size_t abase = (size_t)(r0 + ll) * HDIM + n * BSZ;

        #pragma unroll
        for (int ks = 0; ks < 4; ++ks) {
            const float* pr = xre + abase + ks * 32 + lq * 8;
            const float* pi = xim + abase + ks * 32 + lq * 8;
            const float4 fr0 = *(const float4*)(pr);
            const float4 fr1 = *(const float4*)(pr + 4);
            const float4 fi0 = *(const float4*)(pi);
            const float4 fi1 = *(const float4*)(pi + 4);

            s16x8 br, bi;
            br[0] = (short)f2bf(fr0.x); br[1] = (short)f2bf(fr0.y);
            br[2] = (short)f2bf(fr0.z); br[3] = (short)f2bf(fr0.w);
            br[4] = (short)f2bf(fr1.x); br[5] = (short)f2bf(fr1.y);
            br[6] = (short)f2bf(fr1.z); br[7] = (short)f2bf(fr1.w);
            bi[0] = (short)f2bf(fi0.x); bi[1] = (short)f2bf(fi0.y);
            bi[2] = (short)f2bf(fi0.z); bi[3] = (short)f2bf(fi0.w);
            bi[4] = (short)f2bf(fi1.x); bi[5] = (short)f2bf(fi1.y);
            bi[6] = (short)f2bf(fi1.z); bi[7] = (short)f2bf(fi1.w);
            const s16x8 bin = bi ^ (short)0x8000;   // -xi (bf16 sign flip)

            const bf16x8 axr  = __builtin_bit_cast(bf16x8, br);
            const bf16x8 axi  = __builtin_bit_cast(bf16x8, bi);
            const bf16x8 axin = __builtin_bit_cast(bf16x8, bin);

            #pragma unroll
            for (int cg = 0; cg < 8; ++cg) {
                const int fb = (cg * 4 + ks) * 2;
                const bf16x8 bwr = *(const bf16x8*)&wlds[(fb + 0) * 512 + lane * 8];
                const bf16x8 bwi = *(const bf16x8*)&wlds[(fb + 1) * 512 + lane * 8];
                // out_re = xr@wr - xi@wi ; out_im = xr@wi + xi@wr
                accre[cg] = __builtin_amdgcn_mfma_f32_16x16x32_bf16(axr,  bwr, accre[cg], 0, 0, 0);
                accre[cg] = __builtin_amdgcn_mfma_f32_16x16x32_bf16(axin, bwi, accre[cg], 0, 0, 0);
                accim[cg] = __builtin_amdgcn_mfma_f32_16x16x32_bf16(axr,  bwi, accim[cg], 0, 0, 0);
                accim[cg] = __builtin_amdgcn_mfma_f32_16x16x32_bf16(axi,  bwr, accim[cg], 0, 0, 0);
            }
        }

        // epilogue: C/D layout col = lane&15, row = (lane>>4)*4 + reg
        #pragma unroll
        for (int cg = 0; cg < 8; ++cg) {
            const size_t ocol = (size_t)n * BSZ + cg * 16 + ll;
            #pragma unroll
            for (int r = 0; r < 4; ++r) {
                const int row = r0 + lq * 4 + r;
                float2 v; v.x = accre[cg][r]; v.y = accim[cg][r];
                *(float2*)(out + ((size_t)row * HDIM + ocol) * 2) = v;
            }
        }
    }
}

extern "C" void kernel_launch(void* const* d_in, const int* in_sizes, int n_in,
                              void* d_out, int out_size, void* d_ws, size_t ws_size,
                              hipStream_t stream) {
    const float* xre = (const float*)d_in[0];
    const float* xim = (const float*)d_in[1];
    const float* wgt = (const float*)d_in[2];
    float* out = (float*)d_out;
    (void)in_sizes; (void)n_in; (void)out_size; (void)d_ws; (void)ws_size;

    cbl_main<<<NBLK * WGS_PER_BLK, 512, 0, stream>>>(xre, xim, wgt, out);
}